// Round 11
// baseline (2490.255 us; speedup 1.0000x reference)
//
#include <hip/hip_runtime.h>
#include <math.h>

#define NPTS 16384
#define NCTR 1024
#define BATCH 8
#define NCELL 512  // 8x8x8 Morton cells

typedef unsigned long long u64;
typedef unsigned int u32;

// Bit-exact squared distance matching numpy: ((dx*dx + dy*dy) + dz*dz),
// each op individually IEEE-rounded (no FMA contraction).
__device__ __forceinline__ float sq_dist(float x, float y, float z,
                                         float cx, float cy, float cz) {
  float dx = __fsub_rn(x, cx);
  float dy = __fsub_rn(y, cy);
  float dz = __fsub_rn(z, cz);
  return __fadd_rn(__fadd_rn(__fmul_rn(dx, dx), __fmul_rn(dy, dy)), __fmul_rn(dz, dz));
}

__device__ __forceinline__ float silu_f(float x) {
  return x / (1.0f + __expf(-x));
}

__device__ __forceinline__ u64 kmax(u64 a, u64 b) { return a > b ? a : b; }
__device__ __forceinline__ u64 kmin(u64 a, u64 b) { return a < b ? a : b; }

__device__ __forceinline__ int morton_cell(float x, float y, float z) {
  int mx = min(7, max(0, (int)(x * 8.0f)));
  int my = min(7, max(0, (int)(y * 8.0f)));
  int mz = min(7, max(0, (int)(z * 8.0f)));
  int m = 0;
#pragma unroll
  for (int k = 0; k < 3; ++k) {
    m |= ((mx >> k) & 1) << (3 * k + 2);
    m |= ((my >> k) & 1) << (3 * k + 1);
    m |= ((mz >> k) & 1) << (3 * k + 0);
  }
  return m;
}

// ---------------------------------------------------------------------------
// Kernel 0: DETERMINISTIC Morton counting sort (validated R10). Racy scatter
// of orig-index into LDS, per-cell insertion sort by orig index, deterministic
// rebuild — every launch bit-identical.
// ---------------------------------------------------------------------------
__global__ __launch_bounds__(1024) void sort_kernel(
    const float* __restrict__ xyz, float* __restrict__ sxg,
    float* __restrict__ syg, float* __restrict__ szg, int* __restrict__ sog) {
  const int b = blockIdx.x, t = threadIdx.x;
  const float* X = xyz + (size_t)b * 3 * NPTS;
  const float* Y = X + NPTS;
  const float* Z = X + 2 * NPTS;
  __shared__ int cnt[NCELL];
  __shared__ int off[NCELL];
  __shared__ int start[NCELL];
  __shared__ int so_l[NPTS];
  for (int e = t; e < NCELL; e += 1024) cnt[e] = 0;
  __syncthreads();
#pragma unroll
  for (int j = 0; j < 16; ++j) {
    const int n = t + (j << 10);
    atomicAdd(&cnt[morton_cell(X[n], Y[n], Z[n])], 1);
  }
  __syncthreads();
  if (t < NCELL) off[t] = cnt[t];
  __syncthreads();
  for (int d = 1; d < NCELL; d <<= 1) {
    int v = 0;
    if (t < NCELL) { v = off[t]; if (t >= d) v += off[t - d]; }
    __syncthreads();
    if (t < NCELL) off[t] = v;
    __syncthreads();
  }
  if (t < NCELL) { off[t] -= cnt[t]; start[t] = off[t]; }
  __syncthreads();
#pragma unroll
  for (int j = 0; j < 16; ++j) {
    const int n = t + (j << 10);
    const int pos = atomicAdd(&off[morton_cell(X[n], Y[n], Z[n])], 1);
    so_l[pos] = n;
  }
  __syncthreads();
  if (t < NCELL) {
    const int s0 = start[t], k = cnt[t];
    for (int i2 = 1; i2 < k; ++i2) {
      const int key = so_l[s0 + i2];
      int j2 = i2 - 1;
      while (j2 >= 0 && so_l[s0 + j2] > key) {
        so_l[s0 + j2 + 1] = so_l[s0 + j2];
        --j2;
      }
      so_l[s0 + j2 + 1] = key;
    }
  }
  __syncthreads();
  float* sx = sxg + (size_t)b * NPTS;
  float* sy = syg + (size_t)b * NPTS;
  float* sz = szg + (size_t)b * NPTS;
  int* so = sog + (size_t)b * NPTS;
#pragma unroll
  for (int j = 0; j < 16; ++j) {
    const int pos = t + (j << 10);
    const int n = so_l[pos];
    so[pos] = n;
    sx[pos] = X[n];
    sy[pos] = Y[n];
    sz[pos] = Z[n];
  }
}

// ---------------------------------------------------------------------------
// Kernel 1: chunk-pruned FPS. R10 showed the step is issue-bound on (a) all
// 16 waves redundantly serial-scanning the block reduce and (b) the updating
// wave walking all 1024 pts. Fixes:
//  - per-chunk (64 sorted pts, 1/lane) bboxes in lane c's regs; one vector
//    pass tests all 16 chunks -> ballot mask -> uniform branch skips chunks.
//    Skip test lb_c*0.9999 >= wave-max: same bit-exact no-op-elision proof
//    as the R8/R10 wave-level test.
//  - per-lane chunk keys ck (dist folded in u64 key: kmin == fmin on d);
//    wave candidate = 15-kmax tree + one butterfly.
//  - block reduce: 1 b64 read + 4-level 16-lane butterfly (was 16 reads +
//    15 serial kmax in every thread).
//  - winner z shipped via LDS (owner-lane select + shuffle, update path
//    only) -> no per-step global load at all.
// Keys unique (orig n unique) => ties == jnp.argmax first-occurrence.
// ---------------------------------------------------------------------------
#define CH_LIST(F) \
  F(0)  F(1)  F(2)  F(3)  F(4)  F(5)  F(6)  F(7)  \
  F(8)  F(9)  F(10) F(11) F(12) F(13) F(14) F(15)

__global__ __launch_bounds__(1024)
void fps_kernel(const float* __restrict__ xyz, const float* __restrict__ sxg,
                const float* __restrict__ syg, const float* __restrict__ szg,
                const int* __restrict__ sog, int* __restrict__ fps_idx) {
  const int b = blockIdx.x;
  const int t = threadIdx.x;
  const int w = t >> 6, lane = t & 63;
  const float* X = xyz + (size_t)b * 3 * NPTS;
  const float* Y = X + NPTS;
  const float* Z = X + 2 * NPTS;
  const float* SX = sxg + (size_t)b * NPTS;
  const float* SY = syg + (size_t)b * NPTS;
  const float* SZ = szg + (size_t)b * NPTS;
  const int* SO = sog + (size_t)b * NPTS;

  __shared__ float sxy[2 * NPTS];  // 128 KB interleaved sorted x,y
  __shared__ u64 s_key[32];        // [parity][16 waves]
  __shared__ float s_cz[32];       // winner-z per wave, same parity scheme

#define DECL_CH(c) float z##c; u64 ck##c;
  CH_LIST(DECL_CH)
#undef DECL_CH
  // lane c holds chunk c's bbox (lanes 16-63: inert zeros, ballot-masked)
  float bmnx = 0.f, bmxx = 0.f, bmny = 0.f, bmxy = 0.f, bmnz = 0.f, bmxz = 0.f;

#define INIT_CH(c)                                                      \
  {                                                                     \
    const int p = (w << 10) + (c << 6) + lane;                          \
    const float xv = SX[p], yv = SY[p], zv = SZ[p];                     \
    sxy[2 * p] = xv;                                                    \
    sxy[2 * p + 1] = yv;                                                \
    z##c = zv;                                                          \
    ck##c = ((u64)0x7F800000u << 32) |                                  \
            (u64)(((u32)(16383 - SO[p]) << 14) | (u32)p);               \
    float ax = xv, bx = xv, ay = yv, by = yv, az = zv, bz = zv;         \
    for (int off = 32; off >= 1; off >>= 1) {                           \
      ax = fminf(ax, __shfl_xor(ax, off));                              \
      bx = fmaxf(bx, __shfl_xor(bx, off));                              \
      ay = fminf(ay, __shfl_xor(ay, off));                              \
      by = fmaxf(by, __shfl_xor(by, off));                              \
      az = fminf(az, __shfl_xor(az, off));                              \
      bz = fmaxf(bz, __shfl_xor(bz, off));                              \
    }                                                                   \
    if (lane == c) {                                                    \
      bmnx = ax; bmxx = bx; bmny = ay; bmxy = by; bmnz = az; bmxz = bz; \
    }                                                                   \
  }
  CH_LIST(INIT_CH)
#undef INIT_CH

#define PIN_CH(c) asm volatile("" : "+v"(z##c));
  CH_LIST(PIN_CH)
#undef PIN_CH

  if (t == 0) fps_idx[b * NCTR] = 0;
  __syncthreads();  // LDS staging complete

  float cx = X[0], cy = Y[0], cz = Z[0];
  u64 gkey = ((u64)0x7F800000u << 32);  // +inf value => full update at i=1
  float cz_cand = 0.f;

  for (int i = 1; i < NCTR; ++i) {
    // one vector pass: lane c tests chunk c against the wave's current max
    const float wv = __uint_as_float((u32)(gkey >> 32));
    const float ux = fmaxf(fmaxf(__fsub_rn(bmnx, cx), __fsub_rn(cx, bmxx)), 0.f);
    const float uy = fmaxf(fmaxf(__fsub_rn(bmny, cy), __fsub_rn(cy, bmxy)), 0.f);
    const float uz = fmaxf(fmaxf(__fsub_rn(bmnz, cz), __fsub_rn(cz, bmxz)), 0.f);
    const float lb = __fadd_rn(__fadd_rn(__fmul_rn(ux, ux), __fmul_rn(uy, uy)),
                               __fmul_rn(uz, uz));
    const bool upd = !(__fmul_rn(lb, 0.9999f) >= wv);
    const u32 msk = (u32)(__ballot(upd) & 0xFFFFull);

    if (msk != 0u) {
#define UPD_CH(c)                                                           \
      if (msk & (1u << c)) {                                                \
        const int p = (w << 10) + (c << 6) + lane;                          \
        const float2 xy = *(const float2*)(sxy + 2 * p);                    \
        const float dd = sq_dist(xy.x, xy.y, z##c, cx, cy, cz);             \
        const u64 nk = ((u64)__float_as_uint(dd) << 32) | (u64)(u32)ck##c;  \
        ck##c = kmin(ck##c, nk);                                            \
      }
      CH_LIST(UPD_CH)
#undef UPD_CH
      u64 k = kmax(kmax(kmax(ck0, ck1), kmax(ck2, ck3)),
                   kmax(kmax(ck4, ck5), kmax(ck6, ck7)));
      k = kmax(k, kmax(kmax(kmax(ck8, ck9), kmax(ck10, ck11)),
                       kmax(kmax(ck12, ck13), kmax(ck14, ck15))));
#pragma unroll
      for (int off = 32; off >= 1; off >>= 1)
        k = kmax(k, __shfl_xor(k, off));
      gkey = k;
      // ship the candidate's z: owner-lane 16-way select + broadcast
      const u32 pw_ = (u32)k & 0x3FFFu;
      const int cc = (int)((pw_ >> 6) & 15u);
      float zs = z0;
      zs = (cc == 1) ? z1 : zs;
      zs = (cc == 2) ? z2 : zs;
      zs = (cc == 3) ? z3 : zs;
      zs = (cc == 4) ? z4 : zs;
      zs = (cc == 5) ? z5 : zs;
      zs = (cc == 6) ? z6 : zs;
      zs = (cc == 7) ? z7 : zs;
      zs = (cc == 8) ? z8 : zs;
      zs = (cc == 9) ? z9 : zs;
      zs = (cc == 10) ? z10 : zs;
      zs = (cc == 11) ? z11 : zs;
      zs = (cc == 12) ? z12 : zs;
      zs = (cc == 13) ? z13 : zs;
      zs = (cc == 14) ? z14 : zs;
      cz_cand = __shfl((cc == 15) ? z15 : zs, (int)(pw_ & 63u));
    }
    const int base = (i & 1) << 4;
    if (lane == 0) {
      s_key[base + w] = gkey;
      s_cz[base + w] = cz_cand;
    }
    __syncthreads();  // the ONLY barrier per step

    // block reduce: 1 b64 read + 4-level butterfly over 16 (all lanes converge)
    u64 m = s_key[base + (lane & 15)];
#pragma unroll
    for (int off = 8; off >= 1; off >>= 1)
      m = kmax(m, __shfl_xor(m, off));

    const u32 lowb = (u32)m;
    const int pg = (int)(lowb & 0x3FFFu);
    if (t == 0) fps_idx[b * NCTR + i] = 16383 - (int)((lowb >> 14) & 0x3FFFu);

    const int pu = __builtin_amdgcn_readfirstlane(pg);
    const float2 cxy = *(const float2*)(sxy + 2 * pu);  // one ds_read_b64
    cx = cxy.x;
    cy = cxy.y;
    cz = s_cz[base + (pu >> 10)];  // winner z via LDS broadcast — no global load
  }
}

// ---------------------------------------------------------------------------
// Kernel 2: ball query (unchanged). One wave per centroid; first 32 hits in
// ascending index order, pad with first hit.
// ---------------------------------------------------------------------------
__global__ __launch_bounds__(256) void ballq_kernel(const float* __restrict__ xyz,
                                                    const int* __restrict__ fps_idx,
                                                    int* __restrict__ ball_idx) {
  const int gw = (blockIdx.x * 256 + threadIdx.x) >> 6;  // 0..8191
  const int lane = threadIdx.x & 63;
  const int b = gw >> 10;
  const float* X = xyz + (size_t)b * 3 * NPTS;
  const float* Y = X + NPTS;
  const float* Z = X + 2 * NPTS;
  const int c = fps_idx[gw];
  const float cx = X[c], cy = Y[c], cz = Z[c];
  int* out = ball_idx + (size_t)gw * 32;
  const float R2 = 0.04f;

  int cnt = 0, first = -1;
  for (int base = 0; base < NPTS; base += 64) {
    const int j = base + lane;
    const float d = sq_dist(X[j], Y[j], Z[j], cx, cy, cz);
    const bool inb = !(d > R2);
    const unsigned long long m = __ballot(inb);
    if (first < 0 && m != 0ull) first = base + __ffsll(m) - 1;
    if (inb) {
      const int pos = cnt + __popcll(m & ((1ull << lane) - 1ull));
      if (pos < 32) out[pos] = j;
    }
    cnt += __popcll(m);
    if (cnt >= 32) break;
  }
  for (int k = cnt + lane; k < 32; k += 64) out[k] = first;
}

// ---------------------------------------------------------------------------
// Kernel 2b: one-off weight transpose into workspace (unchanged).
// ---------------------------------------------------------------------------
__global__ __launch_bounds__(256) void transpose_w_kernel(
    const float* __restrict__ w0, const float* __restrict__ w1,
    const float* __restrict__ w2, float* __restrict__ wt0,
    float* __restrict__ wt1, float* __restrict__ wt2) {
  const int t0 = blockIdx.x * 256 + threadIdx.x;
  const int stride = gridDim.x * 256;
  for (int e = t0; e < 64 * 67; e += stride) {
    int o = e / 67, c = e - o * 67;
    wt0[c * 64 + o] = w0[e];
  }
  for (int e = t0; e < 128 * 64; e += stride) {
    int o = e >> 6, c = e & 63;
    wt1[c * 128 + o] = w1[e];
  }
  for (int e = t0; e < 256 * 128; e += stride) {
    int o = e >> 7, c = e & 127;
    wt2[c * 256 + o] = w2[e];
  }
}

// ---------------------------------------------------------------------------
// Kernel 3: fused gather + MLP + mean. NEW: 512-thread blocks, 2 groups per
// block (g = t>>8, per-group code identical to R10's proven version) —
// weights staged ONCE per 2 groups (staging was ~40% of mlp issue).
// LDS ~128 KB: Wt2 chunk aliases dead A0+Wt0 region. 1 block/CU, 2 w/SIMD.
// ---------------------------------------------------------------------------
__global__ __launch_bounds__(512, 1) void mlp_kernel(
    const float* __restrict__ xyz, const float* __restrict__ points,
    const int* __restrict__ fps_idx, const int* __restrict__ ball_idx,
    const float* __restrict__ wt0, const float* __restrict__ b0,
    const float* __restrict__ wt1, const float* __restrict__ b1,
    const float* __restrict__ wt2, const float* __restrict__ b2,
    float* __restrict__ out) {
  const int b = blockIdx.y, t = threadIdx.x;
  const int g = t >> 8, tt = t & 255;
  const int s = blockIdx.x * 2 + g;

  __shared__ float Wt1s[64 * 132];    // 8448 floats, resident
  __shared__ float A1[2 * 64 * 36];   // 4608
  __shared__ float A2[2 * 128 * 36];  // 9216
  __shared__ float R1[9380];          // A0 x2 (4824) + Wt0 (4556) | Wt2 chunk (8704)
  __shared__ float bias0_sh[64];
  __shared__ float bias1_sh[128];
  __shared__ float bias2_sh[64];
  __shared__ int jidx[64];
  __shared__ float ctr[8];

  float* A0 = R1 + g * 2412;      // [67][36] per group
  float* Wt0s = R1 + 4824;        // [67][68]
  float* Wt2s = R1;               // [128][68] per chunk (aliases dead A0+Wt0)
  float* A1g = A1 + g * (64 * 36);
  float* A2g = A2 + g * (128 * 36);

  const int gq = b * NCTR + s;

  // phase 1: stage Wt0, Wt1, biases 0/1, per-group indices + centroid
  if (tt < 32) jidx[g * 32 + tt] = ball_idx[(size_t)gq * 32 + tt];
  if (tt < 3) ctr[g * 4 + tt] = xyz[((size_t)b * 3 + tt) * NPTS + fps_idx[gq]];
  for (int e = t; e < 67 * 64; e += 512) {
    int c = e >> 6, o = e & 63;
    Wt0s[c * 68 + o] = wt0[e];
  }
  for (int e = t; e < 128 * 64; e += 512) {
    int c = e >> 7, o = e & 127;
    Wt1s[c * 132 + o] = wt1[e];
  }
  if (t < 64) bias0_sh[t] = b0[t];
  else if (t >= 64 && t < 192) bias1_sh[t - 64] = b1[t - 64];
  __syncthreads();

  // phase 2: gather A0 = [xyz_norm(3); points(64)] x 32 samples, per group
  for (int e = tt; e < 67 * 32; e += 256) {
    int c = e >> 5, k = e & 31;
    int j = jidx[g * 32 + k];
    float v;
    if (c < 3)
      v = xyz[((size_t)b * 3 + c) * NPTS + j] - ctr[g * 4 + c];
    else
      v = points[((size_t)b * 64 + (c - 3)) * NPTS + j];
    A0[c * 36 + k] = v;
  }
  __syncthreads();

  // phase 3: layer 0 (67 -> 64), per group: tile 4k x 2o
  {
    const int o0 = (tt & 31) * 2;
    const int k0 = (tt >> 5) * 4;
    float acc[4][2] = {{0.f, 0.f}, {0.f, 0.f}, {0.f, 0.f}, {0.f, 0.f}};
    for (int c = 0; c < 67; ++c) {
      const float4 a = *(const float4*)(A0 + c * 36 + k0);
      const float wv0 = Wt0s[c * 68 + o0];
      const float wv1 = Wt0s[c * 68 + o0 + 1];
      acc[0][0] = fmaf(a.x, wv0, acc[0][0]);
      acc[1][0] = fmaf(a.y, wv0, acc[1][0]);
      acc[2][0] = fmaf(a.z, wv0, acc[2][0]);
      acc[3][0] = fmaf(a.w, wv0, acc[3][0]);
      acc[0][1] = fmaf(a.x, wv1, acc[0][1]);
      acc[1][1] = fmaf(a.y, wv1, acc[1][1]);
      acc[2][1] = fmaf(a.z, wv1, acc[2][1]);
      acc[3][1] = fmaf(a.w, wv1, acc[3][1]);
    }
#pragma unroll
    for (int i = 0; i < 2; ++i) {
      const float bb = bias0_sh[o0 + i];
      float4 r;
      r.x = silu_f(acc[0][i] + bb);
      r.y = silu_f(acc[1][i] + bb);
      r.z = silu_f(acc[2][i] + bb);
      r.w = silu_f(acc[3][i] + bb);
      *(float4*)(A1g + (o0 + i) * 36 + k0) = r;
    }
  }
  __syncthreads();

  // phase 4: layer 1 (64 -> 128), per group: tile 4k x 4o (Wt1 already staged)
  {
    const int o0 = (tt & 31) * 4;
    const int k0 = (tt >> 5) * 4;
    float acc[4][4];
#pragma unroll
    for (int kk = 0; kk < 4; ++kk)
#pragma unroll
      for (int oo = 0; oo < 4; ++oo) acc[kk][oo] = 0.f;
    for (int c = 0; c < 64; ++c) {
      const float4 a = *(const float4*)(A1g + c * 36 + k0);
      const float4 wq = *(const float4*)(Wt1s + c * 132 + o0);
      const float av[4] = {a.x, a.y, a.z, a.w};
      const float wv[4] = {wq.x, wq.y, wq.z, wq.w};
#pragma unroll
      for (int kk = 0; kk < 4; ++kk)
#pragma unroll
        for (int oo = 0; oo < 4; ++oo)
          acc[kk][oo] = fmaf(av[kk], wv[oo], acc[kk][oo]);
    }
#pragma unroll
    for (int oo = 0; oo < 4; ++oo) {
      const float bb = bias1_sh[o0 + oo];
      float4 r;
      r.x = silu_f(acc[0][oo] + bb);
      r.y = silu_f(acc[1][oo] + bb);
      r.z = silu_f(acc[2][oo] + bb);
      r.w = silu_f(acc[3][oo] + bb);
      *(float4*)(A2g + (o0 + oo) * 36 + k0) = r;
    }
  }
  __syncthreads();

  // phase 5: layer 2 (128 -> 256) in 4 chunks of 64 outputs + mean over k
  float* P = A1g;  // partial sums [64][9] per group (A1 dead)
  const int o0 = (tt & 31) * 2;
  const int k0 = (tt >> 5) * 4;
  const int kg = tt >> 5;
  for (int chunk = 0; chunk < 4; ++chunk) {
    for (int e = t; e < 64 * 128; e += 512) {
      int c = e >> 6, o = e & 63;
      Wt2s[c * 68 + o] = wt2[c * 256 + chunk * 64 + o];  // coalesced / stride-1
    }
    if (t < 64) bias2_sh[t] = b2[chunk * 64 + t];
    __syncthreads();

    float acc[4][2] = {{0.f, 0.f}, {0.f, 0.f}, {0.f, 0.f}, {0.f, 0.f}};
    for (int c = 0; c < 128; ++c) {
      const float4 a = *(const float4*)(A2g + c * 36 + k0);
      const float wv0 = Wt2s[c * 68 + o0];
      const float wv1 = Wt2s[c * 68 + o0 + 1];
      acc[0][0] = fmaf(a.x, wv0, acc[0][0]);
      acc[1][0] = fmaf(a.y, wv0, acc[1][0]);
      acc[2][0] = fmaf(a.z, wv0, acc[2][0]);
      acc[3][0] = fmaf(a.w, wv0, acc[3][0]);
      acc[0][1] = fmaf(a.x, wv1, acc[0][1]);
      acc[1][1] = fmaf(a.y, wv1, acc[1][1]);
      acc[2][1] = fmaf(a.z, wv1, acc[2][1]);
      acc[3][1] = fmaf(a.w, wv1, acc[3][1]);
    }
#pragma unroll
    for (int i = 0; i < 2; ++i) {
      const float bb = bias2_sh[o0 + i];
      float sum = silu_f(acc[0][i] + bb) + silu_f(acc[1][i] + bb) +
                  silu_f(acc[2][i] + bb) + silu_f(acc[3][i] + bb);
      P[(o0 + i) * 9 + kg] = sum;
    }
    __syncthreads();
    if (tt < 64) {
      float tot = 0.f;
#pragma unroll
      for (int q = 0; q < 8; ++q) tot += P[tt * 9 + q];
      out[((size_t)b * 256 + chunk * 64 + tt) * NCTR + s] = tot * (1.0f / 32.0f);
    }
    __syncthreads();
  }
}

extern "C" void kernel_launch(void* const* d_in, const int* in_sizes, int n_in,
                              void* d_out, int out_size, void* d_ws, size_t ws_size,
                              hipStream_t stream) {
  const float* xyz = (const float*)d_in[0];
  const float* points = (const float*)d_in[1];
  const float* w0 = (const float*)d_in[2];
  const float* b0 = (const float*)d_in[3];
  const float* w1 = (const float*)d_in[4];
  const float* b1 = (const float*)d_in[5];
  const float* w2 = (const float*)d_in[6];
  const float* b2 = (const float*)d_in[7];
  float* out = (float*)d_out;

  int* fps = (int*)d_ws;                       // 8K ints
  int* bidx = (int*)d_ws + 8192;               // 256K ints
  float* wt0 = (float*)d_ws + 270336;          // 67*64
  float* wt1 = wt0 + 67 * 64;                  // 64*128
  float* wt2 = wt1 + 64 * 128;                 // 128*256
  float* sxg = (float*)d_ws + 315584;          // 8*16384 sorted x
  float* syg = sxg + BATCH * NPTS;             // sorted y
  float* szg = syg + BATCH * NPTS;             // sorted z
  int* sog = (int*)(szg + BATCH * NPTS);       // sorted orig idx (~3.4 MB total)

  transpose_w_kernel<<<64, 256, 0, stream>>>(w0, w1, w2, wt0, wt1, wt2);
  sort_kernel<<<BATCH, 1024, 0, stream>>>(xyz, sxg, syg, szg, sog);
  fps_kernel<<<BATCH, 1024, 0, stream>>>(xyz, sxg, syg, szg, sog, fps);
  ballq_kernel<<<2048, 256, 0, stream>>>(xyz, fps, bidx);
  mlp_kernel<<<dim3(512, BATCH), 512, 0, stream>>>(xyz, points, fps, bidx,
                                                   wt0, b0, wt1, b1, wt2, b2, out);
}